// Round 6
// baseline (349.151 us; speedup 1.0000x reference)
//
#include <hip/hip_runtime.h>

typedef __attribute__((ext_vector_type(8))) short short8;
typedef __attribute__((ext_vector_type(4))) short bshort4;
typedef __attribute__((ext_vector_type(4))) float floatx4;

__device__ __forceinline__ unsigned short f2bf(float f) {
  union { float f; unsigned u; } v; v.f = f;
  unsigned r = v.u + 0x7fffu + ((v.u >> 16) & 1u);   // RNE
  return (unsigned short)(r >> 16);
}
// round-half-up pack of two floats to bf16x2
__device__ __forceinline__ unsigned pk2(float lo, float hi) {
  union { float f; unsigned u; } a, b; a.f = lo; b.f = hi;
  return ((a.u + 0x8000u) >> 16) | ((b.u + 0x8000u) & 0xffff0000u);
}
// single-op truncating pack (v_perm_b32): hi16(hi):hi16(lo)
__device__ __forceinline__ unsigned pkt(float lo, float hi) {
  union { float f; unsigned u; } a, b; a.f = lo; b.f = hi;
#if __has_builtin(__builtin_amdgcn_perm)
  return __builtin_amdgcn_perm(b.u, a.u, 0x07060302);
#else
  return (b.u & 0xffff0000u) | (a.u >> 16);
#endif
}
__device__ __forceinline__ float bf2f(unsigned short h) {
  union { unsigned u; float f; } v; v.u = ((unsigned)h) << 16; return v.f;
}
__device__ __forceinline__ float fexp2(float x) {
#if __has_builtin(__builtin_amdgcn_exp2f)
  return __builtin_amdgcn_exp2f(x);
#else
  return exp2f(x);
#endif
}
__device__ __forceinline__ void gl2lds16(const void* g, void* l) {
  __builtin_amdgcn_global_load_lds(
      (const __attribute__((address_space(1))) void*)g,
      (__attribute__((address_space(3))) void*)l, 16, 0, 0);
}

#define MFMA16(a, b, c) __builtin_amdgcn_mfma_f32_16x16x32_bf16((a), (b), (c), 0, 0, 0)

#if __has_builtin(__builtin_amdgcn_mfma_f32_16x16x16bf16_1k)
#define HAVE_MFMA16X16 1
#define MFMA16K16(a, b, c) __builtin_amdgcn_mfma_f32_16x16x16bf16_1k((a), (b), (c), 0, 0, 0)
#else
#define HAVE_MFMA16X16 0
#endif

// Q scale: 1/sqrt(64) * log2(e) -> softmax is a bare exp2 of raw scores.
#define QSCALE 0.18033688011112042f

// ---------------------------------------------------------------------------
// Kernel 0: Wt[n][k] bf16, n in [0,192) over {Wq|Wk|Wv}, k in [0,768)
// ---------------------------------------------------------------------------
__global__ void wt_kernel(const float* __restrict__ Wq, const float* __restrict__ Wk,
                          const float* __restrict__ Wv, unsigned short* __restrict__ Wt) {
  int i = blockIdx.x * 256 + threadIdx.x;
  if (i >= 192 * 768) return;
  int n = i / 768, k = i - n * 768;
  const float* W = (n < 64) ? Wq : (n < 128) ? Wk : Wv;
  Wt[i] = f2bf(W[k * 64 + (n & 63)]);
}

// ---------------------------------------------------------------------------
// Kernel 1: QKV GEMM v6. 64 rows/block, N=192, K-step 64. XOR-swizzled As
// (no pad) -> LDS exactly 40KB -> 4 blocks/CU. Fragment reads split around
// the s0 MFMA block to keep peak VGPR under the 128 cap.
// ---------------------------------------------------------------------------
__global__ __launch_bounds__(256, 4) void qkv_kernel(const float* __restrict__ x,
                                                     const unsigned short* __restrict__ Wt,
                                                     unsigned short* __restrict__ Qb,
                                                     unsigned short* __restrict__ Kb,
                                                     unsigned short* __restrict__ Vt) {
  __shared__ __align__(16) unsigned short As[2][64 * 64];  // XOR-swizzled groups
  __shared__ __align__(16) unsigned short Ws[192 * 64];    // XOR-swizzled groups

  int tid = threadIdx.x;
  int wv = tid >> 6, l15 = tid & 15, quad = (tid & 63) >> 4;
  int sw = l15 & 7;
  int r0 = blockIdx.x * 64;

  floatx4 acc[4][3];
#pragma unroll
  for (int mt = 0; mt < 4; ++mt)
#pragma unroll
    for (int nt = 0; nt < 3; ++nt) acc[mt][nt] = (floatx4){0.f, 0.f, 0.f, 0.f};

  int arow = tid >> 2, acg = tid & 3;
  const float* xs = x + (size_t)(r0 + arow) * 768 + acg * 16;
  int ag0 = arow * 64 + (((acg * 2) ^ (arow & 7)) << 3);       // swizzled group slots
  int ag1 = arow * 64 + (((acg * 2 + 1) ^ (arow & 7)) << 3);

  // ---- prologue ----
  {
    float4 f0 = *(const float4*)(xs);
    float4 f1 = *(const float4*)(xs + 4);
    float4 f2 = *(const float4*)(xs + 8);
    float4 f3 = *(const float4*)(xs + 12);
    unsigned u[8] = {pk2(f0.x, f0.y), pk2(f0.z, f0.w), pk2(f1.x, f1.y), pk2(f1.z, f1.w),
                     pk2(f2.x, f2.y), pk2(f2.z, f2.w), pk2(f3.x, f3.y), pk2(f3.z, f3.w)};
    *(short8*)&As[0][ag0] = *(short8*)&u[0];
    *(short8*)&As[0][ag1] = *(short8*)&u[4];
#pragma unroll
    for (int c = 0; c < 6; ++c) {
      int slot = c * 256 + tid;
      int r = slot >> 3, g = slot & 7, gs = g ^ (r & 7);
      gl2lds16(Wt + r * 768 + gs * 8, &Ws[slot * 8]);
    }
  }
  __syncthreads();

  for (int it = 0; it < 12; ++it) {
    int cur = it & 1, nxt = cur ^ 1, k1 = (it + 1) * 64;
    // ---- s=0 fragments + MFMA ----
    {
      short8 af[4], bf[3];
#pragma unroll
      for (int mt = 0; mt < 4; ++mt)
        af[mt] = *(short8*)&As[cur][(mt * 16 + l15) * 64 + ((quad ^ sw) << 3)];
#pragma unroll
      for (int nt = 0; nt < 3; ++nt)
        bf[nt] = *(short8*)&Ws[((wv * 3 + nt) * 16 + l15) * 64 + ((quad ^ sw) << 3)];
#pragma unroll
      for (int mt = 0; mt < 4; ++mt)
#pragma unroll
        for (int nt = 0; nt < 3; ++nt)
          acc[mt][nt] = MFMA16(af[mt], bf[nt], acc[mt][nt]);
    }
    // ---- s=1 fragments (must be read before barrier) ----
    short8 ag[4], bg[3];
#pragma unroll
    for (int mt = 0; mt < 4; ++mt)
      ag[mt] = *(short8*)&As[cur][(mt * 16 + l15) * 64 + (((4 + quad) ^ sw) << 3)];
#pragma unroll
    for (int nt = 0; nt < 3; ++nt)
      bg[nt] = *(short8*)&Ws[((wv * 3 + nt) * 16 + l15) * 64 + (((4 + quad) ^ sw) << 3)];
    float4 f0, f1, f2, f3;
    if (it < 11) {
      f0 = *(const float4*)(xs + k1);
      f1 = *(const float4*)(xs + k1 + 4);
      f2 = *(const float4*)(xs + k1 + 8);
      f3 = *(const float4*)(xs + k1 + 12);
    }
    __syncthreads();   // all As[cur]/Ws reads done
    if (it < 11) {
#pragma unroll
      for (int c = 0; c < 6; ++c) {
        int slot = c * 256 + tid;
        int r = slot >> 3, g = slot & 7, gs = g ^ (r & 7);
        gl2lds16(Wt + r * 768 + k1 + gs * 8, &Ws[slot * 8]);
      }
      unsigned u[8] = {pk2(f0.x, f0.y), pk2(f0.z, f0.w), pk2(f1.x, f1.y), pk2(f1.z, f1.w),
                       pk2(f2.x, f2.y), pk2(f2.z, f2.w), pk2(f3.x, f3.y), pk2(f3.z, f3.w)};
      *(short8*)&As[nxt][ag0] = *(short8*)&u[0];
      *(short8*)&As[nxt][ag1] = *(short8*)&u[4];
    }
#pragma unroll
    for (int mt = 0; mt < 4; ++mt)
#pragma unroll
      for (int nt = 0; nt < 3; ++nt)
        acc[mt][nt] = MFMA16(ag[mt], bg[nt], acc[mt][nt]);
    __syncthreads();   // As[nxt] writes + Ws gl2lds drained
  }

  // ---- epilogue: Q/K direct, V through LDS transpose (reuse As storage) ----
  unsigned short* VL = &As[0][0];   // [hd 64][s 64] stride 72 (4608 <= 8192 shorts)
#pragma unroll
  for (int mt = 0; mt < 4; ++mt)
#pragma unroll
    for (int nt = 0; nt < 3; ++nt)
#pragma unroll
      for (int r = 0; r < 4; ++r) {
        int grow = r0 + mt * 16 + quad * 4 + r;
        int col = (wv * 3 + nt) * 16 + l15;
        float val = acc[mt][nt][r];
        if (col < 64) {
          Qb[(size_t)grow * 64 + col] = f2bf(val * QSCALE);
        } else if (col < 128) {
          Kb[(size_t)grow * 64 + (col - 64)] = f2bf(val);
        } else {
          VL[(col - 128) * 72 + (mt * 16 + quad * 4 + r)] = f2bf(val);
        }
      }
  __syncthreads();
  int bb = r0 >> 13, s0 = r0 & 8191;
#pragma unroll
  for (int c = 0; c < 2; ++c) {
    int chunk = c * 256 + tid;
    int hd = chunk >> 3, sg = chunk & 7;
    short8 vv = *(short8*)&VL[hd * 72 + sg * 8];
    *(short8*)(Vt + ((size_t)(bb * 64 + hd)) * 8192 + s0 + sg * 8) = vv;
  }
}

// ---------------------------------------------------------------------------
// Kernel 2: causal flash attention v6. 4 waves x 32q = 128q blocks, shared
// K/V staging (K dbuf), K-split x4. S^T = K*Q^T; exp2 softmax; PV computed as
// O^T = V^T * P^T via mfma 16x16x16 whose B-layout EQUALS S^T's C-layout —
// P never touches LDS. O^T transposed back through freed Ks in the epilogue.
// LDS 24KB.
// ---------------------------------------------------------------------------
__global__ __launch_bounds__(256, 4) void attn_kernel(const unsigned short* __restrict__ Qb,
                                                      const unsigned short* __restrict__ Kb,
                                                      const unsigned short* __restrict__ Vt,
                                                      unsigned short* __restrict__ Ob,
                                                      float* __restrict__ Lw) {
  __shared__ __align__(16) unsigned short Ks[2][64 * 64];  // [key][d] swizzled
  __shared__ __align__(16) unsigned short Vts[64 * 64];    // [hd][key] swizzled
#if !HAVE_MFMA16X16
  __shared__ __align__(16) unsigned short Ps[4][32 * 64];  // fallback P buffer
#endif

  int tid = threadIdx.x;
  int wv = tid >> 6, ln = tid & 63, l15 = ln & 15, quad = ln >> 4;
  int sw = l15 & 7;
  int bid = blockIdx.x;
  int qt = 63 - (bid >> 4);               // 128q tile, biggest extent first
  int sub = bid & 15, sp = sub >> 2, b = sub & 3;
  int nk = 2 * (qt + 1);
  int g0 = (nk * sp) >> 2, g1 = (nk * (sp + 1)) >> 2;
  int qw = qt * 128 + wv * 32;
  size_t bbase = (size_t)b * 8192;
  const unsigned short* Kbb = Kb + bbase * 64;
  const unsigned short* Vbb = Vt + (size_t)b * 64 * 8192;

  short8 qf[2][2];
#pragma unroll
  for (int t = 0; t < 2; ++t)
#pragma unroll
    for (int s = 0; s < 2; ++s)
      qf[t][s] = *(const short8*)(Qb + (bbase + qw + t * 16 + l15) * 64 + s * 32 + quad * 8);

  // x16 path: oa[mt*2+t] = O^T tile (m=hd mt, n=q t). fallback: oa[t*4+nt] = O tile.
  floatx4 oa[8];
#pragma unroll
  for (int i = 0; i < 8; ++i) oa[i] = (floatx4){0.f, 0.f, 0.f, 0.f};
  float lp[2] = {0.f, 0.f};
#if !HAVE_MFMA16X16
  unsigned short* Pw = &Ps[wv][0];
#endif

  if (g0 < g1) {
#pragma unroll
    for (int c = 0; c < 2; ++c) {
      int slot = c * 256 + tid;
      int r = slot >> 3, g = slot & 7, gs = g ^ (r & 7);
      gl2lds16(Kbb + (size_t)(g0 * 64 + r) * 64 + gs * 8, &Ks[0][slot * 8]);
    }
    __syncthreads();

    for (int g = g0; g < g1; ++g) {
      int cur = (g - g0) & 1, kb = g << 6;
#pragma unroll
      for (int c = 0; c < 2; ++c) {
        int slot = c * 256 + tid;
        int r = slot >> 3, gg = slot & 7, gs = gg ^ (r & 7);
        gl2lds16(Vbb + (size_t)r * 8192 + kb + gs * 8, &Vts[slot * 8]);
      }
      if (g + 1 < g1) {
#pragma unroll
        for (int c = 0; c < 2; ++c) {
          int slot = c * 256 + tid;
          int r = slot >> 3, gg = slot & 7, gs = gg ^ (r & 7);
          gl2lds16(Kbb + (size_t)(kb + 64 + r) * 64 + gs * 8, &Ks[cur ^ 1][slot * 8]);
        }
      }

      bool active = kb < qw + 32;
      bool edge = kb + 64 > qw;
      floatx4 sc[4][2];
      if (active) {
        // ---- S^T = K * Q^T ----
#pragma unroll
        for (int mt = 0; mt < 4; ++mt) {
          int krow = mt * 16 + l15;
          short8 k0 = *(short8*)&Ks[cur][krow * 64 + ((quad ^ sw) << 3)];
          short8 k1 = *(short8*)&Ks[cur][krow * 64 + (((4 + quad) ^ sw) << 3)];
#pragma unroll
          for (int t = 0; t < 2; ++t) {
            floatx4 z = (floatx4){0.f, 0.f, 0.f, 0.f};
            z = MFMA16(k0, qf[t][0], z);
            sc[mt][t] = MFMA16(k1, qf[t][1], z);
          }
        }
        // ---- exp2 (wave-uniform branch keeps mask off the common path) ----
        if (edge) {
#pragma unroll
          for (int t = 0; t < 2; ++t) {
            int qg = qw + t * 16 + l15;
#pragma unroll
            for (int mt = 0; mt < 4; ++mt)
#pragma unroll
              for (int r = 0; r < 4; ++r) {
                float e = fexp2(sc[mt][t][r]);
                int kg = kb + mt * 16 + quad * 4 + r;
                if (kg > qg) e = 0.f;
                sc[mt][t][r] = e;
                lp[t] += e;
              }
          }
        } else {
#pragma unroll
          for (int t = 0; t < 2; ++t)
#pragma unroll
            for (int mt = 0; mt < 4; ++mt)
#pragma unroll
              for (int r = 0; r < 4; ++r) {
                float e = fexp2(sc[mt][t][r]);
                sc[mt][t][r] = e;
                lp[t] += e;
              }
        }
#if !HAVE_MFMA16X16
        // fallback: P -> LDS (b64, swizzled)
#pragma unroll
        for (int t = 0; t < 2; ++t)
#pragma unroll
          for (int mt = 0; mt < 4; ++mt) {
            int row = t * 16 + l15;
            int sgw = (mt * 4 + quad) ^ (sw << 1);
            unsigned long long dd = (unsigned long long)pk2(sc[mt][t][0], sc[mt][t][1]) |
                                    ((unsigned long long)pk2(sc[mt][t][2], sc[mt][t][3]) << 32);
            *(unsigned long long*)&Pw[row * 64 + sgw * 4] = dd;
          }
#endif
      }
      __syncthreads();   // V(g) + K(g+1) landed; all Ks[cur] reads done

      if (active) {
#if HAVE_MFMA16X16
        // ---- O^T += V^T P^T : B = packed P straight from sc registers ----
#pragma unroll
        for (int ks = 0; ks < 4; ++ks) {
          bshort4 bp[2];
#pragma unroll
          for (int t = 0; t < 2; ++t) {
            union { unsigned u[2]; bshort4 v; } cv;
            cv.u[0] = pkt(sc[ks][t][0], sc[ks][t][1]);
            cv.u[1] = pkt(sc[ks][t][2], sc[ks][t][3]);
            bp[t] = cv.v;
          }
          int gvt = (((ks * 2 + (quad >> 1)) ^ sw) << 3) + (quad & 1) * 4;
#pragma unroll
          for (int mt = 0; mt < 4; ++mt) {
            bshort4 av = *(bshort4*)&Vts[(mt * 16 + l15) * 64 + gvt];
            oa[mt * 2 + 0] = MFMA16K16(av, bp[0], oa[mt * 2 + 0]);
            oa[mt * 2 + 1] = MFMA16K16(av, bp[1], oa[mt * 2 + 1]);
          }
        }
#else
        // ---- fallback: O += P V via LDS P ----
#pragma unroll
        for (int s = 0; s < 2; ++s) {
          short8 pA[2];
#pragma unroll
          for (int t = 0; t < 2; ++t)
            pA[t] = *(short8*)&Pw[(t * 16 + l15) * 64 + (((s * 8 + quad * 2) ^ (sw << 1)) << 2)];
#pragma unroll
          for (int nt = 0; nt < 4; ++nt) {
            short8 vf = *(short8*)&Vts[(nt * 16 + l15) * 64 + (((s * 4 + quad) ^ sw) << 3)];
#pragma unroll
            for (int t = 0; t < 2; ++t) oa[t * 4 + nt] = MFMA16(pA[t], vf, oa[t * 4 + nt]);
          }
        }
#endif
      }
      __syncthreads();   // protect Vts/Ks before next stage
    }
  }

  // ---- epilogue ----
  int hb = sp * 4 + b;
#pragma unroll
  for (int t = 0; t < 2; ++t) {
    float l = lp[t];
    l += __shfl_xor(l, 16);
    l += __shfl_xor(l, 32);
    if (quad == t) Lw[(size_t)hb * 8192 + qw + t * 16 + l15] = l;
  }
#if HAVE_MFMA16X16
  __syncthreads();                         // all staging use done; reuse Ks
  unsigned short* Tw = (unsigned short*)Ks + wv * 2048;   // 32q x 64hd swizzled
#pragma unroll
  for (int mt = 0; mt < 4; ++mt)
#pragma unroll
    for (int t = 0; t < 2; ++t) {
      unsigned long long dd = (unsigned long long)pk2(oa[mt * 2 + t][0], oa[mt * 2 + t][1]) |
                              ((unsigned long long)pk2(oa[mt * 2 + t][2], oa[mt * 2 + t][3]) << 32);
      int qn = t * 16 + l15;
      int addr = qn * 64 + ((((2 * mt + (quad >> 1)) ^ sw)) << 3) + (quad & 1) * 4;
      *(unsigned long long*)&Tw[addr] = dd;
    }
#pragma unroll
  for (int p = 0; p < 4; ++p) {
    int flat = p * 512 + ln * 8;
    int q = flat >> 6, hd0 = flat & 63;
    short8 row = *(short8*)&Tw[q * 64 + (((hd0 >> 3) ^ (q & 7)) << 3)];
    *(short8*)(Ob + ((size_t)hb * 8192 + qw + q) * 64 + hd0) = row;
  }
#else
#pragma unroll
  for (int t = 0; t < 2; ++t)
#pragma unroll
    for (int nt = 0; nt < 4; ++nt)
#pragma unroll
      for (int r = 0; r < 4; ++r) {
        int ql = qw + t * 16 + quad * 4 + r;
        Ob[((size_t)hb * 8192 + ql) * 64 + nt * 16 + l15] = f2bf(oa[t * 4 + nt][r]);
      }
#endif
}

// ---------------------------------------------------------------------------
// Kernel 3: combine 4 K-split partials: out = (sum O_s) / (sum l_s)
// ---------------------------------------------------------------------------
__global__ __launch_bounds__(256) void combine_kernel(const unsigned short* __restrict__ Ob,
                                                      const float* __restrict__ Lw,
                                                      float* __restrict__ out) {
  int idx = (blockIdx.x * 256 + threadIdx.x) * 4;
  int r = idx >> 6, hd = idx & 63;
  float inv = 1.f / (Lw[r] + Lw[32768 + r] + Lw[65536 + r] + Lw[98304 + r]);
  float o0 = 0.f, o1 = 0.f, o2 = 0.f, o3 = 0.f;
#pragma unroll
  for (int sp = 0; sp < 4; ++sp) {
    uint2 a = *(const uint2*)(Ob + (size_t)sp * 32768 * 64 + (size_t)r * 64 + hd);
    o0 += bf2f((unsigned short)(a.x & 0xffff));
    o1 += bf2f((unsigned short)(a.x >> 16));
    o2 += bf2f((unsigned short)(a.y & 0xffff));
    o3 += bf2f((unsigned short)(a.y >> 16));
  }
  float4 o = {o0 * inv, o1 * inv, o2 * inv, o3 * inv};
  *(float4*)(out + idx) = o;
}

// ---------------------------------------------------------------------------
extern "C" void kernel_launch(void* const* d_in, const int* in_sizes, int n_in,
                              void* d_out, int out_size, void* d_ws, size_t ws_size,
                              hipStream_t stream) {
  const float* x  = (const float*)d_in[0];
  const float* Wq = (const float*)d_in[1];
  const float* Wk = (const float*)d_in[2];
  const float* Wv = (const float*)d_in[3];
  float* out = (float*)d_out;

  const size_t M = (size_t)4 * 8192;                 // 32768 rows
  unsigned short* Qb = (unsigned short*)d_ws;        // [32768][64] bf16 (Q*scale*log2e)
  unsigned short* Kb = Qb + M * 64;                  // [32768][64] bf16
  unsigned short* Vt = Kb + M * 64;                  // [4][64][8192] bf16 (V^T)
  unsigned short* Wt = Vt + M * 64;                  // [192][768] bf16 (W^T)
  unsigned short* Ob = Wt + (size_t)192 * 768;       // [4][4][8192][64] bf16 partial O
  float*          Lw = (float*)(Ob + (size_t)4 * M * 64);  // [4][4][8192] partial l

  wt_kernel<<<576, 256, 0, stream>>>(Wq, Wk, Wv, Wt);
  qkv_kernel<<<512, 256, 0, stream>>>(x, Wt, Qb, Kb, Vt);
  attn_kernel<<<1024, 256, 0, stream>>>(Qb, Kb, Vt, Ob, Lw);
  combine_kernel<<<2048, 256, 0, stream>>>(Ob, Lw, out);
}

// Round 7
// 230.967 us; speedup vs baseline: 1.5117x; 1.5117x over previous
//
#include <hip/hip_runtime.h>

typedef __attribute__((ext_vector_type(8))) short short8;
typedef __attribute__((ext_vector_type(4))) short bshort4;
typedef __attribute__((ext_vector_type(4))) float floatx4;

__device__ __forceinline__ unsigned short f2bf(float f) {
  union { float f; unsigned u; } v; v.f = f;
  unsigned r = v.u + 0x7fffu + ((v.u >> 16) & 1u);   // RNE
  return (unsigned short)(r >> 16);
}
// round-half-up pack of two floats to bf16x2
__device__ __forceinline__ unsigned pk2(float lo, float hi) {
  union { float f; unsigned u; } a, b; a.f = lo; b.f = hi;
  return ((a.u + 0x8000u) >> 16) | ((b.u + 0x8000u) & 0xffff0000u);
}
// single-op truncating pack (v_perm_b32): hi16(hi):hi16(lo)
__device__ __forceinline__ unsigned pkt(float lo, float hi) {
  union { float f; unsigned u; } a, b; a.f = lo; b.f = hi;
#if __has_builtin(__builtin_amdgcn_perm)
  return __builtin_amdgcn_perm(b.u, a.u, 0x07060302);
#else
  return (b.u & 0xffff0000u) | (a.u >> 16);
#endif
}
__device__ __forceinline__ float bf2f(unsigned short h) {
  union { unsigned u; float f; } v; v.u = ((unsigned)h) << 16; return v.f;
}
__device__ __forceinline__ float fexp2(float x) {
#if __has_builtin(__builtin_amdgcn_exp2f)
  return __builtin_amdgcn_exp2f(x);
#else
  return exp2f(x);
#endif
}
__device__ __forceinline__ void gl2lds16(const void* g, void* l) {
  __builtin_amdgcn_global_load_lds(
      (const __attribute__((address_space(1))) void*)g,
      (__attribute__((address_space(3))) void*)l, 16, 0, 0);
}

#define MFMA16(a, b, c) __builtin_amdgcn_mfma_f32_16x16x32_bf16((a), (b), (c), 0, 0, 0)

#if __has_builtin(__builtin_amdgcn_mfma_f32_16x16x16bf16_1k)
#define HAVE_MFMA16X16 1
#define MFMA16K16(a, b, c) __builtin_amdgcn_mfma_f32_16x16x16bf16_1k((a), (b), (c), 0, 0, 0)
#else
#define HAVE_MFMA16X16 0
#endif

// Q scale: 1/sqrt(64) * log2(e) -> softmax is a bare exp2 of raw scores.
#define QSCALE 0.18033688011112042f

// ---------------------------------------------------------------------------
// Kernel 0: Wt[n][k] bf16, n in [0,192) over {Wq|Wk|Wv}, k in [0,768)
// ---------------------------------------------------------------------------
__global__ void wt_kernel(const float* __restrict__ Wq, const float* __restrict__ Wk,
                          const float* __restrict__ Wv, unsigned short* __restrict__ Wt) {
  int i = blockIdx.x * 256 + threadIdx.x;
  if (i >= 192 * 768) return;
  int n = i / 768, k = i - n * 768;
  const float* W = (n < 64) ? Wq : (n < 128) ? Wk : Wv;
  Wt[i] = f2bf(W[k * 64 + (n & 63)]);
}

// ---------------------------------------------------------------------------
// Kernel 1: QKV GEMM v7. 64 rows/block, N=192, K-step 64. SINGLE-buffered
// As (8 KB) + Ws (24 KB) -> LDS 32 KB -> 4 blocks/CU. Fragments go to regs
// before the mid barrier; s0/s1 reads split around s0-MFMAs to cap VGPR.
// ---------------------------------------------------------------------------
__global__ __launch_bounds__(256, 4) void qkv_kernel(const float* __restrict__ x,
                                                     const unsigned short* __restrict__ Wt,
                                                     unsigned short* __restrict__ Qb,
                                                     unsigned short* __restrict__ Kb,
                                                     unsigned short* __restrict__ Vt) {
  __shared__ __align__(16) unsigned short As[64 * 64];   // XOR-swizzled groups
  __shared__ __align__(16) unsigned short Ws[192 * 64];  // XOR-swizzled groups

  int tid = threadIdx.x;
  int wv = tid >> 6, l15 = tid & 15, quad = (tid & 63) >> 4;
  int sw = l15 & 7;
  int r0 = blockIdx.x * 64;

  floatx4 acc[4][3];
#pragma unroll
  for (int mt = 0; mt < 4; ++mt)
#pragma unroll
    for (int nt = 0; nt < 3; ++nt) acc[mt][nt] = (floatx4){0.f, 0.f, 0.f, 0.f};

  int arow = tid >> 2, acg = tid & 3;
  const float* xs = x + (size_t)(r0 + arow) * 768 + acg * 16;
  int ag0 = arow * 64 + (((acg * 2) ^ (arow & 7)) << 3);
  int ag1 = arow * 64 + (((acg * 2 + 1) ^ (arow & 7)) << 3);

  // ---- prologue: cvt+write As chunk 0; async-stage Ws chunk 0 ----
  {
    float4 f0 = *(const float4*)(xs);
    float4 f1 = *(const float4*)(xs + 4);
    float4 f2 = *(const float4*)(xs + 8);
    float4 f3 = *(const float4*)(xs + 12);
    unsigned u[8] = {pk2(f0.x, f0.y), pk2(f0.z, f0.w), pk2(f1.x, f1.y), pk2(f1.z, f1.w),
                     pk2(f2.x, f2.y), pk2(f2.z, f2.w), pk2(f3.x, f3.y), pk2(f3.z, f3.w)};
    *(short8*)&As[ag0] = *(short8*)&u[0];
    *(short8*)&As[ag1] = *(short8*)&u[4];
#pragma unroll
    for (int c = 0; c < 6; ++c) {
      int slot = c * 256 + tid;
      int r = slot >> 3, g = slot & 7, gs = g ^ (r & 7);
      gl2lds16(Wt + r * 768 + gs * 8, &Ws[slot * 8]);
    }
  }
  __syncthreads();

  for (int it = 0; it < 12; ++it) {
    int k1 = (it + 1) * 64;
    // ---- s=0 fragments + MFMA ----
    {
      short8 af[4], bf[3];
#pragma unroll
      for (int mt = 0; mt < 4; ++mt)
        af[mt] = *(short8*)&As[(mt * 16 + l15) * 64 + ((quad ^ sw) << 3)];
#pragma unroll
      for (int nt = 0; nt < 3; ++nt)
        bf[nt] = *(short8*)&Ws[((wv * 3 + nt) * 16 + l15) * 64 + ((quad ^ sw) << 3)];
#pragma unroll
      for (int mt = 0; mt < 4; ++mt)
#pragma unroll
        for (int nt = 0; nt < 3; ++nt)
          acc[mt][nt] = MFMA16(af[mt], bf[nt], acc[mt][nt]);
    }
    // ---- s=1 fragments to regs (before overwrite barrier) ----
    short8 ag[4], bg[3];
#pragma unroll
    for (int mt = 0; mt < 4; ++mt)
      ag[mt] = *(short8*)&As[(mt * 16 + l15) * 64 + (((4 + quad) ^ sw) << 3)];
#pragma unroll
    for (int nt = 0; nt < 3; ++nt)
      bg[nt] = *(short8*)&Ws[((wv * 3 + nt) * 16 + l15) * 64 + (((4 + quad) ^ sw) << 3)];
    float4 f0, f1, f2, f3;
    if (it < 11) {
      f0 = *(const float4*)(xs + k1);
      f1 = *(const float4*)(xs + k1 + 4);
      f2 = *(const float4*)(xs + k1 + 8);
      f3 = *(const float4*)(xs + k1 + 12);
    }
    __syncthreads();   // all As/Ws reads done — safe to overwrite
    if (it < 11) {
#pragma unroll
      for (int c = 0; c < 6; ++c) {
        int slot = c * 256 + tid;
        int r = slot >> 3, g = slot & 7, gs = g ^ (r & 7);
        gl2lds16(Wt + r * 768 + k1 + gs * 8, &Ws[slot * 8]);
      }
      unsigned u[8] = {pk2(f0.x, f0.y), pk2(f0.z, f0.w), pk2(f1.x, f1.y), pk2(f1.z, f1.w),
                       pk2(f2.x, f2.y), pk2(f2.z, f2.w), pk2(f3.x, f3.y), pk2(f3.z, f3.w)};
      *(short8*)&As[ag0] = *(short8*)&u[0];
      *(short8*)&As[ag1] = *(short8*)&u[4];
    }
#pragma unroll
    for (int mt = 0; mt < 4; ++mt)
#pragma unroll
      for (int nt = 0; nt < 3; ++nt)
        acc[mt][nt] = MFMA16(ag[mt], bg[nt], acc[mt][nt]);
    __syncthreads();   // As writes + Ws gl2lds drained
  }

  // ---- epilogue: Q/K direct, V through LDS transpose (reuse Ws storage) ----
  unsigned short* VL = &Ws[0];   // [hd 64][s 64] stride 72 (4608 <= 12288 shorts)
#pragma unroll
  for (int mt = 0; mt < 4; ++mt)
#pragma unroll
    for (int nt = 0; nt < 3; ++nt)
#pragma unroll
      for (int r = 0; r < 4; ++r) {
        int grow = r0 + mt * 16 + quad * 4 + r;
        int col = (wv * 3 + nt) * 16 + l15;
        float val = acc[mt][nt][r];
        if (col < 64) {
          Qb[(size_t)grow * 64 + col] = f2bf(val * QSCALE);
        } else if (col < 128) {
          Kb[(size_t)grow * 64 + (col - 64)] = f2bf(val);
        } else {
          VL[(col - 128) * 72 + (mt * 16 + quad * 4 + r)] = f2bf(val);
        }
      }
  __syncthreads();
  int bb = r0 >> 13, s0 = r0 & 8191;
#pragma unroll
  for (int c = 0; c < 2; ++c) {
    int chunk = c * 256 + tid;
    int hd = chunk >> 3, sg = chunk & 7;
    short8 vv = *(short8*)&VL[hd * 72 + sg * 8];
    *(short8*)(Vt + ((size_t)(bb * 64 + hd)) * 8192 + s0 + sg * 8) = vv;
  }
}

// ---------------------------------------------------------------------------
// Kernel 2: causal flash attention v7 = R5 structure + x16 PV with P packed
// to bf16 registers BEFORE the barrier (sc dies in exp phase -> no spill).
// O^T = V^T P^T via mfma 16x16x16 (B-layout == S^T C-layout). LDS 24 KB.
// ---------------------------------------------------------------------------
__global__ __launch_bounds__(256, 4) void attn_kernel(const unsigned short* __restrict__ Qb,
                                                      const unsigned short* __restrict__ Kb,
                                                      const unsigned short* __restrict__ Vt,
                                                      unsigned short* __restrict__ Ob,
                                                      float* __restrict__ Lw) {
  __shared__ __align__(16) unsigned short Ks[2][64 * 64];  // [key][d] swizzled
  __shared__ __align__(16) unsigned short Vts[64 * 64];    // [hd][key] swizzled
#if !HAVE_MFMA16X16
  __shared__ __align__(16) unsigned short Ps[4][32 * 64];  // fallback P buffer
#endif

  int tid = threadIdx.x;
  int wv = tid >> 6, ln = tid & 63, l15 = ln & 15, quad = ln >> 4;
  int sw = l15 & 7;
  int bid = blockIdx.x;
  int qt = 63 - (bid >> 4);               // 128q tile, biggest extent first
  int sub = bid & 15, sp = sub >> 2, b = sub & 3;
  int nk = 2 * (qt + 1);
  int g0 = (nk * sp) >> 2, g1 = (nk * (sp + 1)) >> 2;
  int qw = qt * 128 + wv * 32;
  size_t bbase = (size_t)b * 8192;
  const unsigned short* Kbb = Kb + bbase * 64;
  const unsigned short* Vbb = Vt + (size_t)b * 64 * 8192;

  short8 qf[2][2];
#pragma unroll
  for (int t = 0; t < 2; ++t)
#pragma unroll
    for (int s = 0; s < 2; ++s)
      qf[t][s] = *(const short8*)(Qb + (bbase + qw + t * 16 + l15) * 64 + s * 32 + quad * 8);

  // x16 path: oa[mt*2+t] = O^T tile (m=hd, n=q). fallback: oa[t*4+nt] = O tile.
  floatx4 oa[8];
#pragma unroll
  for (int i = 0; i < 8; ++i) oa[i] = (floatx4){0.f, 0.f, 0.f, 0.f};
  float lp[2] = {0.f, 0.f};
#if !HAVE_MFMA16X16
  unsigned short* Pw = &Ps[wv][0];
#endif

  if (g0 < g1) {
#pragma unroll
    for (int c = 0; c < 2; ++c) {
      int slot = c * 256 + tid;
      int r = slot >> 3, g = slot & 7, gs = g ^ (r & 7);
      gl2lds16(Kbb + (size_t)(g0 * 64 + r) * 64 + gs * 8, &Ks[0][slot * 8]);
    }
    __syncthreads();

    for (int g = g0; g < g1; ++g) {
      int cur = (g - g0) & 1, kb = g << 6;
#pragma unroll
      for (int c = 0; c < 2; ++c) {
        int slot = c * 256 + tid;
        int r = slot >> 3, gg = slot & 7, gs = gg ^ (r & 7);
        gl2lds16(Vbb + (size_t)r * 8192 + kb + gs * 8, &Vts[slot * 8]);
      }
      if (g + 1 < g1) {
#pragma unroll
        for (int c = 0; c < 2; ++c) {
          int slot = c * 256 + tid;
          int r = slot >> 3, gg = slot & 7, gs = gg ^ (r & 7);
          gl2lds16(Kbb + (size_t)(kb + 64 + r) * 64 + gs * 8, &Ks[cur ^ 1][slot * 8]);
        }
      }

      bool active = kb < qw + 32;
      bool edge = kb + 64 > qw;
#if HAVE_MFMA16X16
      bshort4 bp[4][2];   // packed P, the ONLY per-iter state crossing the barrier
#endif
      if (active) {
        // ---- S^T = K * Q^T ----
        floatx4 sc[4][2];
#pragma unroll
        for (int mt = 0; mt < 4; ++mt) {
          int krow = mt * 16 + l15;
          short8 k0 = *(short8*)&Ks[cur][krow * 64 + ((quad ^ sw) << 3)];
          short8 k1 = *(short8*)&Ks[cur][krow * 64 + (((4 + quad) ^ sw) << 3)];
#pragma unroll
          for (int t = 0; t < 2; ++t) {
            floatx4 z = (floatx4){0.f, 0.f, 0.f, 0.f};
            z = MFMA16(k0, qf[t][0], z);
            sc[mt][t] = MFMA16(k1, qf[t][1], z);
          }
        }
        // ---- exp2, causal mask on edge tiles, pack P to bf16 regs ----
#pragma unroll
        for (int t = 0; t < 2; ++t) {
          int qg = qw + t * 16 + l15;
#pragma unroll
          for (int mt = 0; mt < 4; ++mt) {
            float p[4];
#pragma unroll
            for (int r = 0; r < 4; ++r) {
              float e = fexp2(sc[mt][t][r]);
              if (edge) {
                int kg = kb + mt * 16 + quad * 4 + r;
                if (kg > qg) e = 0.f;
              }
              p[r] = e;
              lp[t] += e;
            }
#if HAVE_MFMA16X16
            union { unsigned u[2]; bshort4 v; } cv;
            cv.u[0] = pkt(p[0], p[1]);
            cv.u[1] = pkt(p[2], p[3]);
            bp[mt][t] = cv.v;
#else
            int row = t * 16 + l15;
            int sgw = (mt * 4 + quad) ^ (sw << 1);
            unsigned long long dd = (unsigned long long)pk2(p[0], p[1]) |
                                    ((unsigned long long)pk2(p[2], p[3]) << 32);
            *(unsigned long long*)&Pw[row * 64 + sgw * 4] = dd;
#endif
          }
        }
      }
      __syncthreads();   // V(g) + K(g+1) landed; all Ks[cur] reads done

      if (active) {
#if HAVE_MFMA16X16
        // ---- O^T += V^T P^T : B operand straight from bp registers ----
#pragma unroll
        for (int ks = 0; ks < 4; ++ks) {
          int gvt = (((ks * 2 + (quad >> 1)) ^ sw) << 3) + (quad & 1) * 4;
#pragma unroll
          for (int mt = 0; mt < 4; ++mt) {
            bshort4 av = *(bshort4*)&Vts[(mt * 16 + l15) * 64 + gvt];
            oa[mt * 2 + 0] = MFMA16K16(av, bp[ks][0], oa[mt * 2 + 0]);
            oa[mt * 2 + 1] = MFMA16K16(av, bp[ks][1], oa[mt * 2 + 1]);
          }
        }
#else
#pragma unroll
        for (int s = 0; s < 2; ++s) {
          short8 pA[2];
#pragma unroll
          for (int t = 0; t < 2; ++t)
            pA[t] = *(short8*)&Pw[(t * 16 + l15) * 64 + (((s * 8 + quad * 2) ^ (sw << 1)) << 2)];
#pragma unroll
          for (int nt = 0; nt < 4; ++nt) {
            short8 vf = *(short8*)&Vts[(nt * 16 + l15) * 64 + (((s * 4 + quad) ^ sw) << 3)];
#pragma unroll
            for (int t = 0; t < 2; ++t) oa[t * 4 + nt] = MFMA16(pA[t], vf, oa[t * 4 + nt]);
          }
        }
#endif
      }
      __syncthreads();   // protect Vts/Ks before next stage
    }
  }

  // ---- epilogue ----
  int hb = sp * 4 + b;
#pragma unroll
  for (int t = 0; t < 2; ++t) {
    float l = lp[t];
    l += __shfl_xor(l, 16);
    l += __shfl_xor(l, 32);
    if (quad == t) Lw[(size_t)hb * 8192 + qw + t * 16 + l15] = l;
  }
#if HAVE_MFMA16X16
  __syncthreads();                         // staging done; reuse Ks as transpose buf
  unsigned short* Tw = (unsigned short*)Ks + wv * 2048;   // 32q x 64hd swizzled
#pragma unroll
  for (int mt = 0; mt < 4; ++mt)
#pragma unroll
    for (int t = 0; t < 2; ++t) {
      unsigned long long dd = (unsigned long long)pk2(oa[mt * 2 + t][0], oa[mt * 2 + t][1]) |
                              ((unsigned long long)pk2(oa[mt * 2 + t][2], oa[mt * 2 + t][3]) << 32);
      int qn = t * 16 + l15;
      int addr = qn * 64 + (((2 * mt + (quad >> 1)) ^ sw) << 3) + (quad & 1) * 4;
      *(unsigned long long*)&Tw[addr] = dd;
    }
#pragma unroll
  for (int p = 0; p < 4; ++p) {
    int flat = p * 512 + ln * 8;
    int q = flat >> 6, hd0 = flat & 63;
    short8 row = *(short8*)&Tw[q * 64 + (((hd0 >> 3) ^ (q & 7)) << 3)];
    *(short8*)(Ob + ((size_t)hb * 8192 + qw + q) * 64 + hd0) = row;
  }
#else
#pragma unroll
  for (int t = 0; t < 2; ++t)
#pragma unroll
    for (int nt = 0; nt < 4; ++nt)
#pragma unroll
      for (int r = 0; r < 4; ++r) {
        int ql = qw + t * 16 + quad * 4 + r;
        Ob[((size_t)hb * 8192 + ql) * 64 + nt * 16 + l15] = f2bf(oa[t * 4 + nt][r]);
      }
#endif
}

// ---------------------------------------------------------------------------
// Kernel 3: combine 4 K-split partials: out = (sum O_s) / (sum l_s)
// ---------------------------------------------------------------------------
__global__ __launch_bounds__(256) void combine_kernel(const unsigned short* __restrict__ Ob,
                                                      const float* __restrict__ Lw,
                                                      float* __restrict__ out) {
  int idx = (blockIdx.x * 256 + threadIdx.x) * 4;
  int r = idx >> 6, hd = idx & 63;
  float inv = 1.f / (Lw[r] + Lw[32768 + r] + Lw[65536 + r] + Lw[98304 + r]);
  float o0 = 0.f, o1 = 0.f, o2 = 0.f, o3 = 0.f;
#pragma unroll
  for (int sp = 0; sp < 4; ++sp) {
    uint2 a = *(const uint2*)(Ob + (size_t)sp * 32768 * 64 + (size_t)r * 64 + hd);
    o0 += bf2f((unsigned short)(a.x & 0xffff));
    o1 += bf2f((unsigned short)(a.x >> 16));
    o2 += bf2f((unsigned short)(a.y & 0xffff));
    o3 += bf2f((unsigned short)(a.y >> 16));
  }
  float4 o = {o0 * inv, o1 * inv, o2 * inv, o3 * inv};
  *(float4*)(out + idx) = o;
}

// ---------------------------------------------------------------------------
extern "C" void kernel_launch(void* const* d_in, const int* in_sizes, int n_in,
                              void* d_out, int out_size, void* d_ws, size_t ws_size,
                              hipStream_t stream) {
  const float* x  = (const float*)d_in[0];
  const float* Wq = (const float*)d_in[1];
  const float* Wk = (const float*)d_in[2];
  const float* Wv = (const float*)d_in[3];
  float* out = (float*)d_out;

  const size_t M = (size_t)4 * 8192;                 // 32768 rows
  unsigned short* Qb = (unsigned short*)d_ws;        // [32768][64] bf16 (Q*scale*log2e)
  unsigned short* Kb = Qb + M * 64;                  // [32768][64] bf16
  unsigned short* Vt = Kb + M * 64;                  // [4][64][8192] bf16 (V^T)
  unsigned short* Wt = Vt + M * 64;                  // [192][768] bf16 (W^T)
  unsigned short* Ob = Wt + (size_t)192 * 768;       // [4][4][8192][64] bf16 partial O
  float*          Lw = (float*)(Ob + (size_t)4 * M * 64);  // [4][4][8192] partial l

  wt_kernel<<<576, 256, 0, stream>>>(Wq, Wk, Wv, Wt);
  qkv_kernel<<<512, 256, 0, stream>>>(x, Wt, Qb, Kb, Vt);
  attn_kernel<<<1024, 256, 0, stream>>>(Qb, Kb, Vt, Ob, Lw);
  combine_kernel<<<2048, 256, 0, stream>>>(Ob, Lw, out);
}